// Round 2
// baseline (387.139 us; speedup 1.0000x reference)
//
#include <hip/hip_runtime.h>

#define B_ 64
#define C_ 128
#define T_ 128
#define J_ 25
#define PIT 136   // kernel2 LDS pitch (ushorts): 272B rows, 16B aligned
#define XP 40     // x/F tile pitch (ushorts): 80B rows, 16B aligned
#define GP 136    // G^T pitch

typedef unsigned short ushort_t;
typedef __attribute__((ext_vector_type(8))) unsigned short ushort8;
typedef __attribute__((ext_vector_type(4))) unsigned short ushort4_t;
typedef __attribute__((ext_vector_type(8))) _Float16 half8;
typedef __attribute__((ext_vector_type(4))) float f32x4;

__device__ __forceinline__ float bf2f(ushort_t u) {
  unsigned int v = ((unsigned int)u) << 16;
  return __builtin_bit_cast(float, v);
}
__device__ __forceinline__ ushort_t f2bf(float f) {
  unsigned int u = __builtin_bit_cast(unsigned int, f);
  u += 0x7FFFu + ((u >> 16) & 1u);
  return (ushort_t)(u >> 16);
}
__device__ __forceinline__ ushort_t f2h_bits(float f) {
  _Float16 h = (_Float16)f;
  return __builtin_bit_cast(ushort_t, h);
}
__device__ __forceinline__ half8 cvt_bf8_h8(ushort8 u) {
  half8 r;
#pragma unroll
  for (int i = 0; i < 8; ++i) r[i] = (_Float16)bf2f(u[i]);
  return r;
}

// dual-dtype global accessors (isf32 is wave-uniform)
__device__ __forceinline__ float ldv(const void* p, long i, int isf32) {
  return isf32 ? ((const float*)p)[i] : bf2f(((const ushort_t*)p)[i]);
}
__device__ __forceinline__ half8 ld8h(const void* p, long i, int isf32) {
  half8 r;
  if (isf32) {
    const float* f = (const float*)p + i;
#pragma unroll
    for (int k = 0; k < 8; ++k) r[k] = (_Float16)f[k];
  } else {
    ushort8 u = *(const ushort8*)((const ushort_t*)p + i);
    r = cvt_bf8_h8(u);
  }
  return r;
}
__device__ __forceinline__ void stv(void* p, long i, float v, int isf32) {
  if (isf32) ((float*)p)[i] = v;
  else ((ushort_t*)p)[i] = f2bf(v);
}

// ------------- kernel 0: detect input dtype (f32 vs bf16) -------------------
// Low-half ushorts of f32 words are mantissa bits -> random exponent when
// viewed as bf16 (~8% land in [1e-4,64]). Real bf16 N(0,1) data: ~99%.
__global__ void k_detect(const void* __restrict__ x, int* __restrict__ flag) {
  if (threadIdx.x == 0 && blockIdx.x == 0) {
    const ushort_t* u = (const ushort_t*)x;
    int cnt = 0;
    for (int i = 0; i < 256; ++i) {
      float a = fabsf(bf2f(u[2 * i]));
      if (a > 1e-4f && a < 64.f) cnt++;
    }
    *flag = (cnt > 128) ? 0 : 1;  // mostly plausible -> bf16 (isf32=0)
  }
}

// ---------------- kernel 1: x_t[b,j,c] = mean over T of x[b,c,:,j] ----------
__global__ __launch_bounds__(256) void k_mean(const void* __restrict__ x,
                                              float* __restrict__ xt,
                                              const int* __restrict__ flag) {
  const int isf32 = *flag;
  const int bc = blockIdx.x;  // b*128 + c
  const int b = bc >> 7;
  const long base = (long)bc * (T_ * J_);
  const int j = threadIdx.x & 31, g = threadIdx.x >> 5;  // 8 t-groups of 16
  float s = 0.f;
  if (j < J_) {
    const int t0 = g * 16;
#pragma unroll
    for (int i = 0; i < 16; ++i) s += ldv(x, base + (long)(t0 + i) * J_ + j, isf32);
  }
  __shared__ float red[8][32];
  red[g][j] = s;
  __syncthreads();
  if (threadIdx.x < 32) {
    float tot = 0.f;
#pragma unroll
    for (int gg = 0; gg < 8; ++gg) tot += red[gg][threadIdx.x];
    if (threadIdx.x < J_)
      xt[b * 4096 + threadIdx.x * 128 + (bc & 127)] = tot * (1.0f / 128.0f);
  }
}

// ---------------- kernel 2: per-batch attention -> F[b] (f16), s[b] ---------
__global__ __launch_bounds__(256) void k_attn(
    const float* __restrict__ xt, const void* __restrict__ adj,
    const void* __restrict__ Wk, const void* __restrict__ bk,
    const void* __restrict__ Wq, const void* __restrict__ bq,
    const void* __restrict__ alphap, ushort_t* __restrict__ fkws,
    float* __restrict__ sws, const int* __restrict__ flag) {
  const int isf32 = *flag;
  const int b = blockIdx.x;
  const int tid = threadIdx.x;
  const int wv = tid >> 6, lane = tid & 63, lrow = lane & 15, quad = lane >> 4;
  const float alpha = ldv(alphap, 0, isf32);

  __shared__ __align__(16) ushort_t xtT[32 * PIT];  // f16, [j][c]
  __shared__ __align__(16) ushort_t kkT[32 * PIT];  // f16, [k][o]
  __shared__ __align__(16) ushort_t qqT[32 * PIT];  // f16, [j][o]
  __shared__ float sc[32 * 33];                     // scores then dyn

  for (int idx = tid; idx < 32 * PIT; idx += 256) {
    int r = idx / PIT, col = idx % PIT;
    float v = (r < J_ && col < 128) ? xt[b * 4096 + r * 128 + col] : 0.f;
    xtT[idx] = f2h_bits(v);
  }
  __syncthreads();

  // kk = Wk @ x_t + bk (and qq): M=o(8 tiles, 2/wave), N=j(2 tiles), K=c(4 steps)
  for (int mat = 0; mat < 2; ++mat) {
    const void* W = mat ? Wq : Wk;
    const void* bias = mat ? bq : bk;
    ushort_t* dstT = mat ? qqT : kkT;
    f32x4 acc[2][2] = {};
    for (int ks = 0; ks < 4; ++ks) {
      half8 bfr[2];
#pragma unroll
      for (int jt = 0; jt < 2; ++jt)
        bfr[jt] = *(const half8*)&xtT[(jt * 16 + lrow) * PIT + ks * 32 + quad * 8];
#pragma unroll
      for (int ot = 0; ot < 2; ++ot) {
        int o = (2 * wv + ot) * 16 + lrow;
        half8 afr = ld8h(W, o * 128 + ks * 32 + quad * 8, isf32);
#pragma unroll
        for (int jt = 0; jt < 2; ++jt)
          acc[ot][jt] = __builtin_amdgcn_mfma_f32_16x16x32_f16(afr, bfr[jt],
                                                               acc[ot][jt], 0, 0, 0);
      }
    }
#pragma unroll
    for (int ot = 0; ot < 2; ++ot) {
      int obase = (2 * wv + ot) * 16 + quad * 4;  // C-layout row = o
#pragma unroll
      for (int jt = 0; jt < 2; ++jt) {
        int j = jt * 16 + lrow;  // C-layout col = j
        ushort_t pack[4];
#pragma unroll
        for (int r = 0; r < 4; ++r)
          pack[r] = f2h_bits(acc[ot][jt][r] + ldv(bias, obase + r, isf32));
        *(ushort4_t*)&dstT[j * PIT + obase] = *(ushort4_t*)pack;
      }
    }
  }
  __syncthreads();

  // scores = qq^T @ kk / sqrt(128): M=j, N=k (2x2 tiles, 1/wave), K=o (4 steps)
  {
    const int mt = wv >> 1, nt = wv & 1;
    f32x4 acc = {};
    for (int ks = 0; ks < 4; ++ks) {
      half8 afr = *(const half8*)&qqT[(mt * 16 + lrow) * PIT + ks * 32 + quad * 8];
      half8 bfr = *(const half8*)&kkT[(nt * 16 + lrow) * PIT + ks * 32 + quad * 8];
      acc = __builtin_amdgcn_mfma_f32_16x16x32_f16(afr, bfr, acc, 0, 0, 0);
    }
    const float rs = 0.08838834764831845f;  // 1/sqrt(128)
#pragma unroll
    for (int r = 0; r < 4; ++r)
      sc[(mt * 16 + quad * 4 + r) * 33 + nt * 16 + lrow] = acc[r] * rs;
  }
  __syncthreads();

  if (tid < J_) {  // softmax over k, row tid
    float m = -1e30f;
    for (int k = 0; k < J_; ++k) m = fmaxf(m, sc[tid * 33 + k]);
    float sum = 0.f;
    for (int k = 0; k < J_; ++k) {
      float e = expf(sc[tid * 33 + k] - m);
      sc[tid * 33 + k] = e;
      sum += e;
    }
    float inv = 1.f / sum;
    for (int k = 0; k < J_; ++k) sc[tid * 33 + k] *= inv;
  }
  __syncthreads();

  // Fk[k][j] = F[j][k] = adj[j,k] + alpha * sum_m adj[j,m]*dyn[m,k], 32x40 padded
  for (int idx = tid; idx < 1280; idx += 256) {
    int k = idx / XP, jj = idx % XP;
    float v = 0.f;
    if (k < J_ && jj < J_) {
      v = ldv(adj, jj * J_ + k, isf32);
      float d = 0.f;
      for (int m = 0; m < J_; ++m) d += ldv(adj, jj * J_ + m, isf32) * sc[m * 33 + k];
      v += alpha * d;
    }
    fkws[b * 1280 + idx] = f2h_bits(v);
  }
  if (tid < 32) {  // s[k] = 1 + alpha * colsum_k(dyn)
    float v = 0.f;
    if (tid < J_) {
      float d = 0.f;
      for (int jj = 0; jj < J_; ++jj) d += sc[jj * 33 + tid];
      v = 1.f + alpha * d;
    }
    sws[b * 32 + tid] = v;
  }
}

// ---------------- kernel 3: out = relu(BN(Ws @ (x_tile @ F) + bs*s)) --------
__global__ __launch_bounds__(256) void k_main(
    const void* __restrict__ x, const void* __restrict__ Ws,
    const void* __restrict__ bs, const void* __restrict__ gamma,
    const void* __restrict__ beta, const void* __restrict__ rmean,
    const void* __restrict__ rvar, const ushort_t* __restrict__ fkws,
    const float* __restrict__ sws, void* __restrict__ out,
    const int* __restrict__ flag) {
  const int isf32 = *flag;
  const int b = blockIdx.x >> 7, t = blockIdx.x & 127;
  const int tid = threadIdx.x;
  const int wv = tid >> 6, lane = tid & 63, lrow = lane & 15, quad = lane >> 4;

  __shared__ __align__(16) ushort_t xl[128 * XP];  // f16 x[c][j], j padded 0
  __shared__ __align__(16) ushort_t fk[32 * XP];   // f16 F^T[k][j]
  __shared__ __align__(16) ushort_t gt[32 * GP];   // f16 G^T[k][c]
  __shared__ float bnscale[128], bnshift[128], bsv[128], sv[32];

  // preload Ws A-fragments into registers (A[m=lrow][k=quad*8+j], contiguous c)
  half8 wsf[2][4];
#pragma unroll
  for (int ot = 0; ot < 2; ++ot) {
    int o = (2 * wv + ot) * 16 + lrow;
#pragma unroll
    for (int ks = 0; ks < 4; ++ks)
      wsf[ot][ks] = ld8h(Ws, o * 128 + ks * 32 + quad * 8, isf32);
  }

  for (int idx = tid; idx < 128 * XP; idx += 256) {
    int c = idx / XP, jj = idx % XP;
    ushort_t v = 0;
    if (jj < J_)
      v = f2h_bits(ldv(x, ((long)(b * 128 + c) * 128 + t) * J_ + jj, isf32));
    xl[idx] = v;
  }
  for (int idx = tid; idx < 1280; idx += 256) fk[idx] = fkws[b * 1280 + idx];
  if (tid < 32) sv[tid] = sws[b * 32 + tid];
  if (tid < 128) {
    float g = ldv(gamma, tid, isf32), v = ldv(rvar, tid, isf32);
    float scl = g * rsqrtf(v + 1e-5f);
    bnscale[tid] = scl;
    bnshift[tid] = ldv(beta, tid, isf32) - ldv(rmean, tid, isf32) * scl;
    bsv[tid] = ldv(bs, tid, isf32);
  }
  __syncthreads();

  // G^T[k][c] = sum_j F^T[k][j]*x[c][j] : M=k(2 tiles), N=c(8 tiles, 2/wave), K=j
  {
    half8 afr[2];
#pragma unroll
    for (int mt = 0; mt < 2; ++mt)
      afr[mt] = *(const half8*)&fk[(mt * 16 + lrow) * XP + quad * 8];
#pragma unroll
    for (int ci = 0; ci < 2; ++ci) {
      int ct = 2 * wv + ci;
      half8 bfr = *(const half8*)&xl[(ct * 16 + lrow) * XP + quad * 8];
      f32x4 accg[2] = {};
#pragma unroll
      for (int mt = 0; mt < 2; ++mt)
        accg[mt] = __builtin_amdgcn_mfma_f32_16x16x32_f16(afr[mt], bfr, accg[mt], 0, 0, 0);
#pragma unroll
      for (int mt = 0; mt < 2; ++mt)
#pragma unroll
        for (int r = 0; r < 4; ++r)
          gt[(mt * 16 + quad * 4 + r) * GP + ct * 16 + lrow] = f2h_bits(accg[mt][r]);
    }
  }
  __syncthreads();

  // H[o][k] = sum_c Ws[o][c]*G^T[k][c] : M=o(2 tiles/wave), N=k(2), K=c(4 steps)
  f32x4 acc[2][2] = {};
  for (int ks = 0; ks < 4; ++ks) {
    half8 bfr[2];
#pragma unroll
    for (int nt = 0; nt < 2; ++nt)
      bfr[nt] = *(const half8*)&gt[(nt * 16 + lrow) * GP + ks * 32 + quad * 8];
#pragma unroll
    for (int ot = 0; ot < 2; ++ot)
#pragma unroll
      for (int nt = 0; nt < 2; ++nt)
        acc[ot][nt] = __builtin_amdgcn_mfma_f32_16x16x32_f16(wsf[ot][ks], bfr[nt],
                                                             acc[ot][nt], 0, 0, 0);
  }

  // epilogue: +bs*s, BN (inference), ReLU, store
#pragma unroll
  for (int nt = 0; nt < 2; ++nt) {
    int k = nt * 16 + lrow;  // C-layout col
    if (k < J_) {
      float svk = sv[k];
#pragma unroll
      for (int ot = 0; ot < 2; ++ot) {
        int obase = (2 * wv + ot) * 16 + quad * 4;  // C-layout rows
#pragma unroll
        for (int r = 0; r < 4; ++r) {
          int o = obase + r;
          float v = acc[ot][nt][r] + bsv[o] * svk;
          v = v * bnscale[o] + bnshift[o];
          v = fmaxf(v, 0.f);
          stv(out, ((long)(b * 128 + o) * 128 + t) * J_ + k, v, isf32);
        }
      }
    }
  }
}

extern "C" void kernel_launch(void* const* d_in, const int* in_sizes, int n_in,
                              void* d_out, int out_size, void* d_ws, size_t ws_size,
                              hipStream_t stream) {
  const void* x = d_in[0];
  const void* adj = d_in[1];
  const void* Wk = d_in[2];
  const void* bk = d_in[3];
  const void* Wq = d_in[4];
  const void* bq = d_in[5];
  const void* Ws = d_in[6];
  const void* bsp = d_in[7];
  const void* gamma = d_in[8];
  const void* beta = d_in[9];
  const void* rmean = d_in[10];
  const void* rvar = d_in[11];
  const void* alphap = d_in[12];

  char* ws = (char*)d_ws;
  int* flag = (int*)ws;                                      // 4 B (+pad to 256)
  float* xt = (float*)(ws + 256);                            // 64*32*128 f32 = 1 MiB
  ushort_t* fkws = (ushort_t*)(ws + 256 + 64 * 4096 * 4);    // 64*1280 f16
  float* sws = (float*)(ws + 256 + 64 * 4096 * 4 + 64 * 1280 * 2);  // 64*32 f32

  k_detect<<<1, 64, 0, stream>>>(x, flag);
  k_mean<<<B_ * C_, 256, 0, stream>>>(x, xt, flag);
  k_attn<<<B_, 256, 0, stream>>>(xt, adj, Wk, bk, Wq, bq, alphap, fkws, sws, flag);
  k_main<<<B_ * T_, 256, 0, stream>>>(x, Ws, bsp, gamma, beta, rmean, rvar, fkws, sws,
                                      d_out, flag);
}

// Round 3
// 319.013 us; speedup vs baseline: 1.2136x; 1.2136x over previous
//
#include <hip/hip_runtime.h>

#define B_ 64
#define C_ 128
#define T_ 128
#define J_ 25
#define PIT 136   // k_attn LDS pitch (ushorts)
#define XP 40     // F/x j-pitch (ushorts)
#define GP 136    // G^T c-pitch (ushorts): 272B rows, 2-way banks, 16B aligned
#define TT 4      // t's per k_main block

typedef unsigned short ushort_t;
typedef __attribute__((ext_vector_type(8))) unsigned short ushort8;
typedef __attribute__((ext_vector_type(4))) unsigned short ushort4_t;
typedef __attribute__((ext_vector_type(8))) _Float16 half8;
typedef __attribute__((ext_vector_type(4))) float f32x4;

__device__ __forceinline__ float bf2f(ushort_t u) {
  unsigned int v = ((unsigned int)u) << 16;
  return __builtin_bit_cast(float, v);
}
__device__ __forceinline__ ushort_t f2bf(float f) {
  unsigned int u = __builtin_bit_cast(unsigned int, f);
  u += 0x7FFFu + ((u >> 16) & 1u);
  return (ushort_t)(u >> 16);
}
__device__ __forceinline__ ushort_t f2h_bits(float f) {
  _Float16 h = (_Float16)f;
  return __builtin_bit_cast(ushort_t, h);
}
__device__ __forceinline__ half8 cvt_bf8_h8(ushort8 u) {
  half8 r;
#pragma unroll
  for (int i = 0; i < 8; ++i) r[i] = (_Float16)bf2f(u[i]);
  return r;
}
__device__ __forceinline__ float ldv(const void* p, long i, int isf32) {
  return isf32 ? ((const float*)p)[i] : bf2f(((const ushort_t*)p)[i]);
}
__device__ __forceinline__ half8 ld8h(const void* p, long i, int isf32) {
  half8 r;
  if (isf32) {
    const float* f = (const float*)p + i;
#pragma unroll
    for (int k = 0; k < 8; ++k) r[k] = (_Float16)f[k];
  } else {
    ushort8 u = *(const ushort8*)((const ushort_t*)p + i);
    r = cvt_bf8_h8(u);
  }
  return r;
}

// ------------- kernel 0: detect input dtype (f32 vs bf16) -------------------
__global__ void k_detect(const void* __restrict__ x, int* __restrict__ flag) {
  if (threadIdx.x == 0 && blockIdx.x == 0) {
    const ushort_t* u = (const ushort_t*)x;
    int cnt = 0;
    for (int i = 0; i < 256; ++i) {
      float a = fabsf(bf2f(u[2 * i]));
      if (a > 1e-4f && a < 64.f) cnt++;
    }
    *flag = (cnt > 128) ? 0 : 1;  // mostly plausible bf16 -> isf32=0
  }
}

// ------------- kernel 1: x_t[b,j,c] = mean over T, LDS-staged ---------------
__global__ __launch_bounds__(256) void k_mean(const void* __restrict__ x,
                                              float* __restrict__ xt,
                                              const int* __restrict__ flag) {
  const int isf32 = *flag;
  const int bc = blockIdx.x;  // b*128 + c
  const int b = bc >> 7, c = bc & 127;
  const long base = (long)bc * 3200;  // elements
  __shared__ float pl[3200];
  __shared__ float red[8][32];
  const int tid = threadIdx.x;
  // coalesced vec4 staging: 800 groups of 4
  if (isf32) {
    const f32x4* src = (const f32x4*)((const float*)x + base);
    for (int i = tid; i < 800; i += 256) *(f32x4*)&pl[i * 4] = src[i];
  } else {
    const ushort4_t* src = (const ushort4_t*)((const ushort_t*)x + base);
    for (int i = tid; i < 800; i += 256) {
      ushort4_t u = src[i];
      f32x4 v;
#pragma unroll
      for (int r = 0; r < 4; ++r) v[r] = bf2f(u[r]);
      *(f32x4*)&pl[i * 4] = v;
    }
  }
  __syncthreads();
  const int j = tid & 31, g = tid >> 5;
  float s = 0.f;
  if (j < J_) {
#pragma unroll
    for (int i = 0; i < 16; ++i) s += pl[(g * 16 + i) * 25 + j];
  }
  red[g][j] = s;
  __syncthreads();
  if (tid < 32) {
    float tot = 0.f;
#pragma unroll
    for (int gg = 0; gg < 8; ++gg) tot += red[gg][tid];
    if (tid < J_) xt[b * 4096 + tid * 128 + c] = tot * (1.0f / 128.0f);
  }
}

// ---------------- kernel 2: per-batch attention -> F[b] (f16), s[b] ---------
__global__ __launch_bounds__(256) void k_attn(
    const float* __restrict__ xt, const void* __restrict__ adj,
    const void* __restrict__ Wk, const void* __restrict__ bk,
    const void* __restrict__ Wq, const void* __restrict__ bq,
    const void* __restrict__ alphap, ushort_t* __restrict__ fkws,
    float* __restrict__ sws, const int* __restrict__ flag) {
  const int isf32 = *flag;
  const int b = blockIdx.x;
  const int tid = threadIdx.x;
  const int wv = tid >> 6, lane = tid & 63, lrow = lane & 15, quad = lane >> 4;
  const float alpha = ldv(alphap, 0, isf32);

  __shared__ __align__(16) ushort_t xtT[32 * PIT];  // f16, [j][c]
  __shared__ __align__(16) ushort_t kkT[32 * PIT];  // f16, [k][o]
  __shared__ __align__(16) ushort_t qqT[32 * PIT];  // f16, [j][o]
  __shared__ float sc[32 * 33];

  for (int idx = tid; idx < 32 * PIT; idx += 256) {
    int r = idx / PIT, col = idx % PIT;
    float v = (r < J_ && col < 128) ? xt[b * 4096 + r * 128 + col] : 0.f;
    xtT[idx] = f2h_bits(v);
  }
  __syncthreads();

  for (int mat = 0; mat < 2; ++mat) {
    const void* W = mat ? Wq : Wk;
    const void* bias = mat ? bq : bk;
    ushort_t* dstT = mat ? qqT : kkT;
    f32x4 acc[2][2] = {};
    for (int ks = 0; ks < 4; ++ks) {
      half8 bfr[2];
#pragma unroll
      for (int jt = 0; jt < 2; ++jt)
        bfr[jt] = *(const half8*)&xtT[(jt * 16 + lrow) * PIT + ks * 32 + quad * 8];
#pragma unroll
      for (int ot = 0; ot < 2; ++ot) {
        int o = (2 * wv + ot) * 16 + lrow;
        half8 afr = ld8h(W, o * 128 + ks * 32 + quad * 8, isf32);
#pragma unroll
        for (int jt = 0; jt < 2; ++jt)
          acc[ot][jt] = __builtin_amdgcn_mfma_f32_16x16x32_f16(afr, bfr[jt],
                                                               acc[ot][jt], 0, 0, 0);
      }
    }
#pragma unroll
    for (int ot = 0; ot < 2; ++ot) {
      int obase = (2 * wv + ot) * 16 + quad * 4;
#pragma unroll
      for (int jt = 0; jt < 2; ++jt) {
        int j = jt * 16 + lrow;
        ushort_t pack[4];
#pragma unroll
        for (int r = 0; r < 4; ++r)
          pack[r] = f2h_bits(acc[ot][jt][r] + ldv(bias, obase + r, isf32));
        *(ushort4_t*)&dstT[j * PIT + obase] = *(ushort4_t*)pack;
      }
    }
  }
  __syncthreads();

  {
    const int mt = wv >> 1, nt = wv & 1;
    f32x4 acc = {};
    for (int ks = 0; ks < 4; ++ks) {
      half8 afr = *(const half8*)&qqT[(mt * 16 + lrow) * PIT + ks * 32 + quad * 8];
      half8 bfr = *(const half8*)&kkT[(nt * 16 + lrow) * PIT + ks * 32 + quad * 8];
      acc = __builtin_amdgcn_mfma_f32_16x16x32_f16(afr, bfr, acc, 0, 0, 0);
    }
    const float rs = 0.08838834764831845f;  // 1/sqrt(128)
#pragma unroll
    for (int r = 0; r < 4; ++r)
      sc[(mt * 16 + quad * 4 + r) * 33 + nt * 16 + lrow] = acc[r] * rs;
  }
  __syncthreads();

  if (tid < J_) {
    float m = -1e30f;
    for (int k = 0; k < J_; ++k) m = fmaxf(m, sc[tid * 33 + k]);
    float sum = 0.f;
    for (int k = 0; k < J_; ++k) {
      float e = expf(sc[tid * 33 + k] - m);
      sc[tid * 33 + k] = e;
      sum += e;
    }
    float inv = 1.f / sum;
    for (int k = 0; k < J_; ++k) sc[tid * 33 + k] *= inv;
  }
  __syncthreads();

  for (int idx = tid; idx < 1280; idx += 256) {
    int k = idx / XP, jj = idx % XP;
    float v = 0.f;
    if (k < J_ && jj < J_) {
      v = ldv(adj, jj * J_ + k, isf32);
      float d = 0.f;
      for (int m = 0; m < J_; ++m) d += ldv(adj, jj * J_ + m, isf32) * sc[m * 33 + k];
      v += alpha * d;
    }
    fkws[b * 1280 + idx] = f2h_bits(v);
  }
  if (tid < 32) {
    float v = 0.f;
    if (tid < J_) {
      float d = 0.f;
      for (int jj = 0; jj < J_; ++jj) d += sc[jj * 33 + tid];
      v = 1.f + alpha * d;
    }
    sws[b * 32 + tid] = v;
  }
}

// ------- kernel 3: per (b, 4 t's): out = relu(BN(Ws @ (x@F) + bs*s)) --------
// LDS map (bytes): fk[0,2560) | X[2560,43520) | gt[43520,73984)
//                  outbuf f32 reuses [2560,53760) after stage B.
#define SM_FK 0
#define SM_X 2560
#define SM_GT 43520
#define SM_TOT 73984
__global__ __launch_bounds__(256, 2) void k_main(
    const void* __restrict__ x, const void* __restrict__ Ws,
    const void* __restrict__ bs, const void* __restrict__ gamma,
    const void* __restrict__ beta, const void* __restrict__ rmean,
    const void* __restrict__ rvar, const ushort_t* __restrict__ fkws,
    const float* __restrict__ sws, void* __restrict__ out,
    const int* __restrict__ flag) {
  const int isf32 = *flag;
  const int b = blockIdx.x >> 5, tb = blockIdx.x & 31, t0 = tb * TT;
  const int tid = threadIdx.x;
  const int wv = tid >> 6, lane = tid & 63, lrow = lane & 15, quad = lane >> 4;

  __shared__ __align__(16) char smem[SM_TOT];
  __shared__ float bnscale[128], bnshift[128], bsv[128], sv[32];
  ushort_t* fk = (ushort_t*)(smem + SM_FK);   // F^T [k][j] pitch 40
  ushort_t* X = (ushort_t*)(smem + SM_X);     // x f16 [t][c][j] pitch 40
  ushort_t* gt = (ushort_t*)(smem + SM_GT);   // G^T f16 [n=(t,k)][c] pitch 136
  float* outbuf = (float*)(smem + SM_X);      // f32 [o][n] pitch 100 (reuse)

  // Ws A-fragments in registers: A[m=o sub][k=c chunk]
  half8 wsf[2][4];
#pragma unroll
  for (int ot = 0; ot < 2; ++ot) {
    int o = (2 * wv + ot) * 16 + lrow;
#pragma unroll
    for (int ks = 0; ks < 4; ++ks)
      wsf[ot][ks] = ld8h(Ws, o * 128 + ks * 32 + quad * 8, isf32);
  }

  // ---- staging: x tile (coalesced vec4), fk, bn, pads ----
  {
    const long fbase = ((long)(b * 128) * 128 + t0) * 25;  // c=0 element base
    if (isf32) {
      const float* xf = (const float*)x + fbase;
      for (int idx = tid; idx < 3200; idx += 256) {
        int c = idx / 25, q = idx % 25;
        f32x4 v = *(const f32x4*)(xf + (long)c * 3200 + q * 4);
#pragma unroll
        for (int r = 0; r < 4; ++r) {
          int p = q * 4 + r, tl = p / 25, j = p % 25;
          X[tl * 5120 + c * XP + j] = f2h_bits(v[r]);
        }
      }
    } else {
      const ushort_t* xh = (const ushort_t*)x + fbase;
      for (int idx = tid; idx < 3200; idx += 256) {
        int c = idx / 25, q = idx % 25;
        ushort4_t u = *(const ushort4_t*)(xh + (long)c * 3200 + q * 4);
#pragma unroll
        for (int r = 0; r < 4; ++r) {
          int p = q * 4 + r, tl = p / 25, j = p % 25;
          X[tl * 5120 + c * XP + j] = f2h_bits(bf2f(u[r]));
        }
      }
    }
    // zero X j-pad [25,32) (read by MFMA K-padding; must be finite/zero)
    for (int idx = tid; idx < 512 * 7; idx += 256) {
      int row = idx / 7, j = 25 + idx % 7;  // row = t*128+c
      X[(row >> 7) * 5120 + (row & 127) * XP + j] = 0;
    }
    // zero gt rows [100,112) cols [0,128)
    for (int idx = tid; idx < 192; idx += 256) {
      int row = 100 + (idx >> 4), col8 = (idx & 15) * 8;
      half8 z = {};
      *(half8*)&gt[row * GP + col8] = z;
    }
    for (int idx = tid; idx < 1280; idx += 256) fk[idx] = fkws[b * 1280 + idx];
    if (tid < 32) sv[tid] = sws[b * 32 + tid];
    if (tid < 128) {
      float g = ldv(gamma, tid, isf32), v = ldv(rvar, tid, isf32);
      float scl = g * rsqrtf(v + 1e-5f);
      bnscale[tid] = scl;
      bnshift[tid] = ldv(beta, tid, isf32) - ldv(rmean, tid, isf32) * scl;
      bsv[tid] = ldv(bs, tid, isf32);
    }
  }
  __syncthreads();

  // ---- stage A: G^T[(t,k)][c] = sum_j F^T[k][j] * x[t][c][j] ----
  {
    half8 afr[2];
#pragma unroll
    for (int mt = 0; mt < 2; ++mt)
      afr[mt] = *(const half8*)&fk[(mt * 16 + lrow) * XP + quad * 8];
#pragma unroll
    for (int t = 0; t < TT; ++t) {
#pragma unroll
      for (int ci = 0; ci < 2; ++ci) {
        int ct = 2 * wv + ci;
        half8 bfr = *(const half8*)&X[t * 5120 + (ct * 16 + lrow) * XP + quad * 8];
        f32x4 accg[2] = {};
#pragma unroll
        for (int mt = 0; mt < 2; ++mt)
          accg[mt] = __builtin_amdgcn_mfma_f32_16x16x32_f16(afr[mt], bfr, accg[mt], 0, 0, 0);
#pragma unroll
        for (int mt = 0; mt < 2; ++mt)
#pragma unroll
          for (int r = 0; r < 4; ++r) {
            int kk = mt * 16 + quad * 4 + r;
            if (kk < J_)
              gt[(t * 25 + kk) * GP + ct * 16 + lrow] = f2h_bits(accg[mt][r]);
          }
      }
    }
  }
  __syncthreads();

  // ---- stage B: H[o][n] = sum_c Ws[o][c] * G^T[n][c], n in [0,112) ----
  f32x4 acc[2][7];
#pragma unroll
  for (int ot = 0; ot < 2; ++ot)
#pragma unroll
    for (int nt = 0; nt < 7; ++nt) acc[ot][nt] = (f32x4){};
  for (int ks = 0; ks < 4; ++ks) {
    half8 bfr[7];
#pragma unroll
    for (int nt = 0; nt < 7; ++nt)
      bfr[nt] = *(const half8*)&gt[(nt * 16 + lrow) * GP + ks * 32 + quad * 8];
#pragma unroll
    for (int ot = 0; ot < 2; ++ot)
#pragma unroll
      for (int nt = 0; nt < 7; ++nt)
        acc[ot][nt] = __builtin_amdgcn_mfma_f32_16x16x32_f16(wsf[ot][ks], bfr[nt],
                                                             acc[ot][nt], 0, 0, 0);
  }
  __syncthreads();  // all gt reads done; outbuf may now overwrite X/gt

  // ---- epilogue into LDS (f32 [o][n] pitch 100) ----
#pragma unroll
  for (int nt = 0; nt < 7; ++nt) {
    int n = nt * 16 + lrow;
    if (n < 100) {
      float svk = sv[n % 25];
#pragma unroll
      for (int ot = 0; ot < 2; ++ot) {
        int obase = (2 * wv + ot) * 16 + quad * 4;
#pragma unroll
        for (int r = 0; r < 4; ++r) {
          int o = obase + r;
          float v = acc[ot][nt][r] + bsv[o] * svk;
          v = v * bnscale[o] + bnshift[o];
          outbuf[o * 100 + n] = fmaxf(v, 0.f);
        }
      }
    }
  }
  __syncthreads();

  // ---- vectorized store: per o, 100 contiguous floats ----
  {
    const long obase = ((long)(b * 128) * 128 + t0) * 25;
    if (isf32) {
      float* of = (float*)out + obase;
      for (int idx = tid; idx < 3200; idx += 256) {
        int o = idx / 25, q = idx % 25;
        *(f32x4*)(of + (long)o * 3200 + q * 4) = *(const f32x4*)&outbuf[o * 100 + q * 4];
      }
    } else {
      ushort_t* oh = (ushort_t*)out + obase;
      for (int idx = tid; idx < 3200; idx += 256) {
        int o = idx / 25, q = idx % 25;
        f32x4 v = *(const f32x4*)&outbuf[o * 100 + q * 4];
        ushort4_t u;
#pragma unroll
        for (int r = 0; r < 4; ++r) u[r] = f2bf(v[r]);
        *(ushort4_t*)(oh + (long)o * 3200 + q * 4) = u;
      }
    }
  }
}

extern "C" void kernel_launch(void* const* d_in, const int* in_sizes, int n_in,
                              void* d_out, int out_size, void* d_ws, size_t ws_size,
                              hipStream_t stream) {
  const void* x = d_in[0];
  const void* adj = d_in[1];
  const void* Wk = d_in[2];
  const void* bk = d_in[3];
  const void* Wq = d_in[4];
  const void* bq = d_in[5];
  const void* Ws = d_in[6];
  const void* bsp = d_in[7];
  const void* gamma = d_in[8];
  const void* beta = d_in[9];
  const void* rmean = d_in[10];
  const void* rvar = d_in[11];
  const void* alphap = d_in[12];

  char* ws = (char*)d_ws;
  int* flag = (int*)ws;
  float* xt = (float*)(ws + 256);
  ushort_t* fkws = (ushort_t*)(ws + 256 + 64 * 4096 * 4);
  float* sws = (float*)(ws + 256 + 64 * 4096 * 4 + 64 * 1280 * 2);

  k_detect<<<1, 64, 0, stream>>>(x, flag);
  k_mean<<<B_ * C_, 256, 0, stream>>>(x, xt, flag);
  k_attn<<<B_, 256, 0, stream>>>(xt, adj, Wk, bk, Wq, bq, alphap, fkws, sws, flag);
  k_main<<<B_ * (T_ / TT), 256, 0, stream>>>(x, Ws, bsp, gamma, beta, rmean, rvar,
                                             fkws, sws, d_out, flag);
}

// Round 4
// 298.434 us; speedup vs baseline: 1.2972x; 1.0690x over previous
//
#include <hip/hip_runtime.h>

#define B_ 64
#define C_ 128
#define T_ 128
#define J_ 25
#define PIT 136   // k_attn LDS pitch (ushorts)
#define XP 40     // F j-pitch (ushorts)
#define GP 136    // G^T c-pitch (ushorts): 272B rows, 16B aligned
#define TT 4      // t's per k_main block

typedef unsigned short ushort_t;
typedef __attribute__((ext_vector_type(8))) unsigned short ushort8;
typedef __attribute__((ext_vector_type(4))) unsigned short ushort4_t;
typedef __attribute__((ext_vector_type(8))) _Float16 half8;
typedef __attribute__((ext_vector_type(4))) float f32x4;
// relaxed-alignment variants for odd-offset x rows
typedef float f32x4u __attribute__((ext_vector_type(4), aligned(4)));
typedef unsigned short ushort8u __attribute__((ext_vector_type(8), aligned(2)));

__device__ __forceinline__ float bf2f(ushort_t u) {
  unsigned int v = ((unsigned int)u) << 16;
  return __builtin_bit_cast(float, v);
}
__device__ __forceinline__ ushort_t f2bf(float f) {
  unsigned int u = __builtin_bit_cast(unsigned int, f);
  u += 0x7FFFu + ((u >> 16) & 1u);
  return (ushort_t)(u >> 16);
}
__device__ __forceinline__ ushort_t f2h_bits(float f) {
  _Float16 h = (_Float16)f;
  return __builtin_bit_cast(ushort_t, h);
}
__device__ __forceinline__ float h2f(ushort_t u) {
  return (float)__builtin_bit_cast(_Float16, u);
}
__device__ __forceinline__ half8 cvt_bf8_h8(ushort8 u) {
  half8 r;
#pragma unroll
  for (int i = 0; i < 8; ++i) r[i] = (_Float16)bf2f(u[i]);
  return r;
}
__device__ __forceinline__ float ldv(const void* p, long i, int isf32) {
  return isf32 ? ((const float*)p)[i] : bf2f(((const ushort_t*)p)[i]);
}
__device__ __forceinline__ half8 ld8h(const void* p, long i, int isf32) {
  half8 r;
  if (isf32) {
    const float* f = (const float*)p + i;
#pragma unroll
    for (int k = 0; k < 8; ++k) r[k] = (_Float16)f[k];
  } else {
    ushort8 u = *(const ushort8*)((const ushort_t*)p + i);
    r = cvt_bf8_h8(u);
  }
  return r;
}

// inline dtype detect: sample 64 consecutive words of a tensor this block reads.
// bf16 data: ~all low-half ushorts plausible as bf16; f32 data: low ushorts are
// mantissa bits -> ~8% plausible. Wave-uniform via ballot; all waves agree.
__device__ __forceinline__ int detect_isf32(const void* p, int tid) {
  const ushort_t* u = (const ushort_t*)p;
  float a = fabsf(bf2f(u[2 * (tid & 63)]));
  int ok = (a > 1e-4f && a < 64.f) ? 1 : 0;
  unsigned long long m = __ballot(ok);
  return (__popcll(m) > 32) ? 0 : 1;
}

// ------------- kernel 1: x_t[b,j,c] = mean over T, LDS-staged ---------------
__global__ __launch_bounds__(256) void k_mean(const void* __restrict__ x,
                                              float* __restrict__ xt) {
  const int bc = blockIdx.x;  // b*128 + c
  const int b = bc >> 7, c = bc & 127;
  const long base = (long)bc * 3200;
  const int tid = threadIdx.x;
  // sample this block's own plane (works for both dtypes: base is elem index;
  // byte offset differs but both land inside x and are x-distributed data)
  const int isf32 = detect_isf32((const ushort_t*)x + base, tid);
  __shared__ float pl[3200];
  __shared__ float red[8][32];
  if (isf32) {
    const f32x4* src = (const f32x4*)((const float*)x + base);
    for (int i = tid; i < 800; i += 256) *(f32x4*)&pl[i * 4] = src[i];
  } else {
    const ushort4_t* src = (const ushort4_t*)((const ushort_t*)x + base);
    for (int i = tid; i < 800; i += 256) {
      ushort4_t u = src[i];
      f32x4 v;
#pragma unroll
      for (int r = 0; r < 4; ++r) v[r] = bf2f(u[r]);
      *(f32x4*)&pl[i * 4] = v;
    }
  }
  __syncthreads();
  const int j = tid & 31, g = tid >> 5;
  float s = 0.f;
  if (j < J_) {
#pragma unroll
    for (int i = 0; i < 16; ++i) s += pl[(g * 16 + i) * 25 + j];
  }
  red[g][j] = s;
  __syncthreads();
  if (tid < 32) {
    float tot = 0.f;
#pragma unroll
    for (int gg = 0; gg < 8; ++gg) tot += red[gg][tid];
    if (tid < J_) xt[b * 4096 + tid * 128 + c] = tot * (1.0f / 128.0f);
  }
}

// ---------------- kernel 2: per-batch attention -> F[b] (f16), s[b] ---------
__global__ __launch_bounds__(256) void k_attn(
    const float* __restrict__ xt, const void* __restrict__ adj,
    const void* __restrict__ Wk, const void* __restrict__ bk,
    const void* __restrict__ Wq, const void* __restrict__ bq,
    const void* __restrict__ alphap, ushort_t* __restrict__ fkws,
    float* __restrict__ sws) {
  const int b = blockIdx.x;
  const int tid = threadIdx.x;
  const int isf32 = detect_isf32(Wk, tid);
  const int wv = tid >> 6, lane = tid & 63, lrow = lane & 15, quad = lane >> 4;
  const float alpha = ldv(alphap, 0, isf32);

  __shared__ __align__(16) ushort_t xtT[32 * PIT];  // f16, [j][c]
  __shared__ __align__(16) ushort_t kkT[32 * PIT];  // f16, [k][o]
  __shared__ __align__(16) ushort_t qqT[32 * PIT];  // f16, [j][o]
  __shared__ float sc[32 * 33];

  for (int idx = tid; idx < 32 * PIT; idx += 256) {
    int r = idx / PIT, col = idx % PIT;
    float v = (r < J_ && col < 128) ? xt[b * 4096 + r * 128 + col] : 0.f;
    xtT[idx] = f2h_bits(v);
  }
  __syncthreads();

  for (int mat = 0; mat < 2; ++mat) {
    const void* W = mat ? Wq : Wk;
    const void* bias = mat ? bq : bk;
    ushort_t* dstT = mat ? qqT : kkT;
    f32x4 acc[2][2] = {};
    for (int ks = 0; ks < 4; ++ks) {
      half8 bfr[2];
#pragma unroll
      for (int jt = 0; jt < 2; ++jt)
        bfr[jt] = *(const half8*)&xtT[(jt * 16 + lrow) * PIT + ks * 32 + quad * 8];
#pragma unroll
      for (int ot = 0; ot < 2; ++ot) {
        int o = (2 * wv + ot) * 16 + lrow;
        half8 afr = ld8h(W, o * 128 + ks * 32 + quad * 8, isf32);
#pragma unroll
        for (int jt = 0; jt < 2; ++jt)
          acc[ot][jt] = __builtin_amdgcn_mfma_f32_16x16x32_f16(afr, bfr[jt],
                                                               acc[ot][jt], 0, 0, 0);
      }
    }
#pragma unroll
    for (int ot = 0; ot < 2; ++ot) {
      int obase = (2 * wv + ot) * 16 + quad * 4;
#pragma unroll
      for (int jt = 0; jt < 2; ++jt) {
        int j = jt * 16 + lrow;
        ushort_t pack[4];
#pragma unroll
        for (int r = 0; r < 4; ++r)
          pack[r] = f2h_bits(acc[ot][jt][r] + ldv(bias, obase + r, isf32));
        *(ushort4_t*)&dstT[j * PIT + obase] = *(ushort4_t*)pack;
      }
    }
  }
  __syncthreads();

  {
    const int mt = wv >> 1, nt = wv & 1;
    f32x4 acc = {};
    for (int ks = 0; ks < 4; ++ks) {
      half8 afr = *(const half8*)&qqT[(mt * 16 + lrow) * PIT + ks * 32 + quad * 8];
      half8 bfr = *(const half8*)&kkT[(nt * 16 + lrow) * PIT + ks * 32 + quad * 8];
      acc = __builtin_amdgcn_mfma_f32_16x16x32_f16(afr, bfr, acc, 0, 0, 0);
    }
    const float rs = 0.08838834764831845f;  // 1/sqrt(128)
#pragma unroll
    for (int r = 0; r < 4; ++r)
      sc[(mt * 16 + quad * 4 + r) * 33 + nt * 16 + lrow] = acc[r] * rs;
  }
  __syncthreads();

  if (tid < J_) {
    float m = -1e30f;
    for (int k = 0; k < J_; ++k) m = fmaxf(m, sc[tid * 33 + k]);
    float sum = 0.f;
    for (int k = 0; k < J_; ++k) {
      float e = expf(sc[tid * 33 + k] - m);
      sc[tid * 33 + k] = e;
      sum += e;
    }
    float inv = 1.f / sum;
    for (int k = 0; k < J_; ++k) sc[tid * 33 + k] *= inv;
  }
  __syncthreads();

  for (int idx = tid; idx < 1280; idx += 256) {
    int k = idx / XP, jj = idx % XP;
    float v = 0.f;
    if (k < J_ && jj < J_) {
      v = ldv(adj, jj * J_ + k, isf32);
      float d = 0.f;
      for (int m = 0; m < J_; ++m) d += ldv(adj, jj * J_ + m, isf32) * sc[m * 33 + k];
      v += alpha * d;
    }
    fkws[b * 1280 + idx] = f2h_bits(v);
  }
  if (tid < 32) {
    float v = 0.f;
    if (tid < J_) {
      float d = 0.f;
      for (int jj = 0; jj < J_; ++jj) d += sc[jj * 33 + tid];
      v = 1.f + alpha * d;
    }
    sws[b * 32 + tid] = v;
  }
}

// ------- kernel 3: per (b, 4 t's): out = relu(BN(Ws @ (x@F) + bs*s)) --------
// LDS: fk [0,2560) | gt [2560,33024); outbuf f16 (128x100, 25600B) reuses gt.
#define SM_FK 0
#define SM_GT 2560
#define SM_TOT 33024
__global__ __launch_bounds__(256, 4) void k_main(
    const void* __restrict__ x, const void* __restrict__ Ws,
    const void* __restrict__ bs, const void* __restrict__ gamma,
    const void* __restrict__ beta, const void* __restrict__ rmean,
    const void* __restrict__ rvar, const ushort_t* __restrict__ fkws,
    const float* __restrict__ sws, void* __restrict__ out) {
  const int tid = threadIdx.x;
  const int isf32 = detect_isf32(Ws, tid);
  const int b = blockIdx.x >> 5, tb = blockIdx.x & 31, t0 = tb * TT;
  const int wv = tid >> 6, lane = tid & 63, lrow = lane & 15, quad = lane >> 4;

  __shared__ __align__(16) char smem[SM_TOT];
  __shared__ float bnscale[128], bnshift[128], bsv[128], sv[32];
  ushort_t* fk = (ushort_t*)(smem + SM_FK);      // F^T [k][j] pitch 40
  ushort_t* gt = (ushort_t*)(smem + SM_GT);      // G^T f16 [n][c] pitch 136
  ushort_t* outbuf = (ushort_t*)(smem + SM_GT);  // f16 [o][n] pitch 100 (reuse)

  // Ws A-fragments in registers
  half8 wsf[2][4];
#pragma unroll
  for (int ot = 0; ot < 2; ++ot) {
    int o = (2 * wv + ot) * 16 + lrow;
#pragma unroll
    for (int ks = 0; ks < 4; ++ks)
      wsf[ot][ks] = ld8h(Ws, o * 128 + ks * 32 + quad * 8, isf32);
  }

  // tiny staging: fk (vec8), gt zero rows [100,112), bn params
  for (int i = tid; i < 160; i += 256)
    *(ushort8*)&fk[i * 8] = *(const ushort8*)&fkws[b * 1280 + i * 8];
  for (int i = tid; i < 204; i += 256) {  // 12 rows x 17 vec8
    int row = 100 + i / 17, col8 = (i % 17) * 8;
    ushort8 z = {};
    *(ushort8*)&gt[row * GP + col8] = z;
  }
  if (tid < 32) sv[tid] = sws[b * 32 + tid];
  if (tid < 128) {
    float g = ldv(gamma, tid, isf32), v = ldv(rvar, tid, isf32);
    float scl = g * rsqrtf(v + 1e-5f);
    bnscale[tid] = scl;
    bnshift[tid] = ldv(beta, tid, isf32) - ldv(rmean, tid, isf32) * scl;
    bsv[tid] = ldv(bs, tid, isf32);
  }
  __syncthreads();

  // ---- stage A: G^T[(t,k)][c] = sum_j F^T[k][j]*x[c][j], x direct-from-global
  // fk cols [25,40) are zero -> K-pad garbage annihilated. quad3 loads only
  // j=24 (scalar) so no OOB past x's end.
  {
    half8 afr[2];
#pragma unroll
    for (int mt = 0; mt < 2; ++mt)
      afr[mt] = *(const half8*)&fk[(mt * 16 + lrow) * XP + quad * 8];
    const float* xf = (const float*)x;
    const ushort_t* xh = (const ushort_t*)x;
#pragma unroll
    for (int t = 0; t < TT; ++t) {
#pragma unroll
      for (int ci = 0; ci < 2; ++ci) {
        int ct = 2 * wv + ci;
        long p = (long)b * 409600 + (long)(ct * 16 + lrow) * 3200 + (t0 + t) * 25;
        half8 bfr;
        if (quad < 3) {
          if (isf32) {
            f32x4u v0 = *(const f32x4u*)(xf + p + quad * 8);
            f32x4u v1 = *(const f32x4u*)(xf + p + quad * 8 + 4);
#pragma unroll
            for (int r = 0; r < 4; ++r) {
              bfr[r] = (_Float16)v0[r];
              bfr[4 + r] = (_Float16)v1[r];
            }
          } else {
            ushort8u u = *(const ushort8u*)(xh + p + quad * 8);
#pragma unroll
            for (int r = 0; r < 8; ++r) bfr[r] = (_Float16)bf2f(u[r]);
          }
        } else {
          bfr = (half8){};
          bfr[0] = (_Float16)(isf32 ? xf[p + 24] : bf2f(xh[p + 24]));
        }
        f32x4 accg[2] = {};
#pragma unroll
        for (int mt = 0; mt < 2; ++mt)
          accg[mt] = __builtin_amdgcn_mfma_f32_16x16x32_f16(afr[mt], bfr, accg[mt], 0, 0, 0);
#pragma unroll
        for (int mt = 0; mt < 2; ++mt)
#pragma unroll
          for (int r = 0; r < 4; ++r) {
            int kk = mt * 16 + quad * 4 + r;
            if (kk < J_)
              gt[(t * 25 + kk) * GP + ct * 16 + lrow] = f2h_bits(accg[mt][r]);
          }
      }
    }
  }
  __syncthreads();

  // ---- stage B: H[o][n] = sum_c Ws[o][c]*G^T[n][c], n in [0,112) ----
  f32x4 acc[2][7];
#pragma unroll
  for (int ot = 0; ot < 2; ++ot)
#pragma unroll
    for (int nt = 0; nt < 7; ++nt) acc[ot][nt] = (f32x4){};
  for (int ks = 0; ks < 4; ++ks) {
#pragma unroll
    for (int nt = 0; nt < 7; ++nt) {
      half8 bfr = *(const half8*)&gt[(nt * 16 + lrow) * GP + ks * 32 + quad * 8];
#pragma unroll
      for (int ot = 0; ot < 2; ++ot)
        acc[ot][nt] = __builtin_amdgcn_mfma_f32_16x16x32_f16(wsf[ot][ks], bfr,
                                                             acc[ot][nt], 0, 0, 0);
    }
  }
  __syncthreads();  // gt reads done; outbuf may overwrite

  // ---- epilogue into LDS f16 [o][n] pitch 100 ----
#pragma unroll
  for (int nt = 0; nt < 7; ++nt) {
    int n = nt * 16 + lrow;
    if (n < 100) {
      float svk = sv[n % 25];
#pragma unroll
      for (int ot = 0; ot < 2; ++ot) {
        int obase = (2 * wv + ot) * 16 + quad * 4;
#pragma unroll
        for (int r = 0; r < 4; ++r) {
          int o = obase + r;
          float v = acc[ot][nt][r] + bsv[o] * svk;
          v = v * bnscale[o] + bnshift[o];
          outbuf[o * 100 + n] = f2h_bits(fmaxf(v, 0.f));
        }
      }
    }
  }
  __syncthreads();

  // ---- vectorized store: per o, 100 contiguous elements ----
  {
    const long obase = ((long)(b * 128) * 128 + t0) * 25;
    if (isf32) {
      float* of = (float*)out + obase;
      for (int idx = tid; idx < 3200; idx += 256) {
        int o = idx / 25, q = idx % 25;
        ushort4_t u = *(const ushort4_t*)&outbuf[o * 100 + q * 4];
        f32x4 v;
#pragma unroll
        for (int r = 0; r < 4; ++r) v[r] = h2f(u[r]);
        *(f32x4*)(of + (long)o * 3200 + q * 4) = v;
      }
    } else {
      ushort_t* oh = (ushort_t*)out + obase;
      for (int idx = tid; idx < 3200; idx += 256) {
        int o = idx / 25, q = idx % 25;
        ushort4_t u = *(const ushort4_t*)&outbuf[o * 100 + q * 4];
        ushort4_t w;
#pragma unroll
        for (int r = 0; r < 4; ++r) w[r] = f2bf(h2f(u[r]));
        *(ushort4_t*)(oh + (long)o * 3200 + q * 4) = w;
      }
    }
  }
}

extern "C" void kernel_launch(void* const* d_in, const int* in_sizes, int n_in,
                              void* d_out, int out_size, void* d_ws, size_t ws_size,
                              hipStream_t stream) {
  const void* x = d_in[0];
  const void* adj = d_in[1];
  const void* Wk = d_in[2];
  const void* bk = d_in[3];
  const void* Wq = d_in[4];
  const void* bq = d_in[5];
  const void* Ws = d_in[6];
  const void* bsp = d_in[7];
  const void* gamma = d_in[8];
  const void* beta = d_in[9];
  const void* rmean = d_in[10];
  const void* rvar = d_in[11];
  const void* alphap = d_in[12];

  char* ws = (char*)d_ws;
  float* xt = (float*)ws;                                  // 64*32*128 f32 = 1 MiB
  ushort_t* fkws = (ushort_t*)(ws + 64 * 4096 * 4);        // 64*1280 f16
  float* sws = (float*)(ws + 64 * 4096 * 4 + 64 * 1280 * 2);

  k_mean<<<B_ * C_, 256, 0, stream>>>(x, xt);
  k_attn<<<B_, 256, 0, stream>>>(xt, adj, Wk, bk, Wq, bq, alphap, fkws, sws);
  k_main<<<B_ * (T_ / TT), 256, 0, stream>>>(x, Ws, bsp, gamma, beta, rmean, rvar,
                                             fkws, sws, d_out);
}